// Round 13
// baseline (879.131 us; speedup 1.0000x reference)
//
#include <hip/hip_runtime.h>
#include <hip/hip_bf16.h>
#include <stdint.h>

// GraphTripleConv: B=32, O=4096, T=16384, D=H=DOUT=128
// out = [new_obj (B*O*128) | new_p (B*T*128)], f32
#define Bn 32
#define On 4096
#define Tn 16384
#define Dn 128

typedef short short8 __attribute__((ext_vector_type(8)));
typedef short short4v __attribute__((ext_vector_type(4)));
typedef float f32x4 __attribute__((ext_vector_type(4)));

__device__ inline short f2bf(float f) {
  union { float f; uint32_t u; } v; v.f = f;
  uint32_t u = v.u;
  uint32_t r = u + 0x7fffu + ((u >> 16) & 1u);  // RNE
  return (short)(r >> 16);
}
__device__ inline float bf2f(unsigned short u) {
  union { uint32_t ui; float f; } cv; cv.ui = ((uint32_t)u) << 16; return cv.f;
}
__device__ inline uint32_t pack2bf(float a, float b) {
  return ((uint32_t)(uint16_t)f2bf(a)) | (((uint32_t)(uint16_t)f2bf(b)) << 16);
}
__device__ inline float bflo(uint32_t u) { union { uint32_t i; float f; } c; c.i = u << 16; return c.f; }
__device__ inline float bfhi(uint32_t u) { union { uint32_t i; float f; } c; c.i = u & 0xffff0000u; return c.f; }

// ---- fused prep+sort (one launch): blocks 0..31 = per-batch counting sort;
// blocks 32..144 = weight prep (f32 [K][N] -> bf16 [N][K], prescaled by g*invs).
__global__ __launch_bounds__(1024) void prep_sort(
    const int* __restrict__ edges, int* __restrict__ hist_g,
    int* __restrict__ offs_g, unsigned short* __restrict__ eidx,
    const float* __restrict__ W1, const float* __restrict__ W2,
    const float* __restrict__ W3, const float* __restrict__ W4,
    const float* __restrict__ b1, const float* __restrict__ g1, const float* __restrict__ be1,
    const float* __restrict__ b2, const float* __restrict__ g2, const float* __restrict__ be2,
    const float* __restrict__ b3, const float* __restrict__ g3, const float* __restrict__ be3,
    const float* __restrict__ b4, const float* __restrict__ g4, const float* __restrict__ be4,
    short* __restrict__ w1t, short* __restrict__ w2t,
    short* __restrict__ w3t, short* __restrict__ w4t,
    float* __restrict__ add1g, float* __restrict__ add2g,
    float* __restrict__ add3g, float* __restrict__ add4g)
{
  if (blockIdx.x >= 32) {
    const float invs = 1.0f / sqrtf(1.001f);
    int i = (blockIdx.x - 32) * 1024 + threadIdx.x;
    if (i < 49152) {
      int n = i / 384, k = i % 384;
      w1t[i] = f2bf(W1[k * 128 + n] * g1[n] * invs);
    } else if (i < 81920) {
      int j = i - 49152;
      int n = j / 128, k = j % 128;
      int c2 = 128 + n;                       // only cols 128..383 live (new_s dead)
      w2t[j] = f2bf(W2[k * 384 + c2] * g2[c2] * invs);
    } else if (i < 98304) {
      int j = i - 81920;
      int n = j / 128, k = j % 128;
      w3t[j] = f2bf(W3[k * 128 + n] * g3[n] * invs);
    } else if (i < 114688) {
      int j = i - 98304;
      int n = j / 128, k = j % 128;
      w4t[j] = f2bf(W4[k * 128 + n] * g4[n] * invs);
    } else if (i < 114816) {
      int n = i - 114688;
      add1g[n] = b1[n] * g1[n] * invs + be1[n];
    } else if (i < 115072) {
      int n = i - 114816;
      int c2 = 128 + n;
      add2g[n] = b2[c2] * g2[c2] * invs + be2[c2];
    } else if (i < 115200) {
      int n = i - 115072;
      add3g[n] = b3[n] * g3[n] * invs + be3[n];
    } else if (i < 115328) {
      int n = i - 115200;
      add4g[n] = b4[n] * g4[n] * invs + be4[n];
    }
    return;
  }
  // ---- sort path
  __shared__ int h[4096];
  __shared__ int of[4096];
  __shared__ int sd[1024];
  int b = blockIdx.x, tid = threadIdx.x;
#pragma unroll
  for (int i = 0; i < 4; i++) h[tid + i * 1024] = 0;
  __syncthreads();
  int ov[16];
#pragma unroll
  for (int j = 0; j < 16; j++) {
    int t = j * 1024 + tid;
    ov[j] = edges[((size_t)(b * Tn + t)) * 2 + 1];
    atomicAdd(&h[ov[j]], 1);
  }
  __syncthreads();
  int base = tid * 4;
  int hh[4]; int s = 0;
#pragma unroll
  for (int j = 0; j < 4; j++) { hh[j] = h[base + j]; s += hh[j]; }
  sd[tid] = s;
  int tsum = s;
  for (int off = 1; off < 1024; off <<= 1) {
    __syncthreads();
    int t = (tid >= off) ? sd[tid - off] : 0;
    __syncthreads();
    sd[tid] += t;
  }
  __syncthreads();
  int excl = sd[tid] - tsum + b * Tn;
#pragma unroll
  for (int j = 0; j < 4; j++) {
    of[base + j] = excl;
    offs_g[b * On + base + j] = excl;
    hist_g[b * On + base + j] = hh[j];
    excl += hh[j];
  }
  __syncthreads();
#pragma unroll
  for (int i = 0; i < 4; i++) h[tid + i * 1024] = 0;   // reuse as fill
  __syncthreads();
#pragma unroll
  for (int j = 0; j < 16; j++) {
    int t = j * 1024 + tid;
    int pos = of[ov[j]] + atomicAdd(&h[ov[j]], 1);
    eidx[pos] = (unsigned short)t;
  }
}

// ---- object projection: objSO[r] = [ objS*gs1+add1 | objO*gs1 ], bf16 (prescaled w1t)
__global__ __launch_bounds__(512, 2) void objproj(
    const float* __restrict__ obj, const short* __restrict__ w1t,
    const float* __restrict__ add1g, unsigned short* __restrict__ objSO)
{
  __shared__ __align__(16) char lds[81920];
  const int WOF = 0, AOF = 65536;
  int tid = threadIdx.x;
  {
    int n = tid >> 2, q = tid & 3;
    int swz = (n & 7) << 4;
    const short* s1 = w1t + n * 384 + q * 32;          // W1s: k 0..127
    const short* s2 = w1t + n * 384 + 256 + q * 32;    // W1o: k 256..383
#pragma unroll
    for (int i = 0; i < 4; i++) {
      *(short8*)(lds + WOF + n * 256 + ((q * 64 + i * 16) ^ swz)) = *(const short8*)(s1 + i * 8);
      *(short8*)(lds + WOF + 32768 + n * 256 + ((q * 64 + i * 16) ^ swz)) = *(const short8*)(s2 + i * 8);
    }
  }
  int wave = tid >> 6, lane = tid & 63;
  int l15 = lane & 15, l4 = lane >> 4;
  int mg = wave >> 2, ng = wave & 3;
  int r = tid >> 3, seg = tid & 7;
  int rswz = (r & 7) << 4;

  for (int it = 0; it < 4; it++) {
    int row0 = (blockIdx.x * 4 + it) * 64;
    if (it) __syncthreads();
    {
      const float* src = obj + (size_t)(row0 + r) * Dn + seg * 16;
      float4 v0 = *(const float4*)(src);
      float4 v1 = *(const float4*)(src + 4);
      float4 v2 = *(const float4*)(src + 8);
      float4 v3 = *(const float4*)(src + 12);
      short8 p0, p1;
      p0[0]=f2bf(v0.x); p0[1]=f2bf(v0.y); p0[2]=f2bf(v0.z); p0[3]=f2bf(v0.w);
      p0[4]=f2bf(v1.x); p0[5]=f2bf(v1.y); p0[6]=f2bf(v1.z); p0[7]=f2bf(v1.w);
      p1[0]=f2bf(v2.x); p1[1]=f2bf(v2.y); p1[2]=f2bf(v2.z); p1[3]=f2bf(v2.w);
      p1[4]=f2bf(v3.x); p1[5]=f2bf(v3.y); p1[6]=f2bf(v3.z); p1[7]=f2bf(v3.w);
      *(short8*)(lds + AOF + r * 256 + ((seg * 32) ^ rswz)) = p0;
      *(short8*)(lds + AOF + r * 256 + ((seg * 32 + 16) ^ rswz)) = p1;
    }
    __syncthreads();
#pragma unroll
    for (int half = 0; half < 2; half++) {
      f32x4 acc[2][2] = {};
#pragma unroll
      for (int kk = 0; kk < 4; kk++) {
        short8 a[2], bb[2];
#pragma unroll
        for (int m = 0; m < 2; m++) {
          int row = mg * 32 + m * 16 + l15;
          a[m] = *(short8*)(lds + AOF + row * 256 + ((kk * 64 + 16 * l4) ^ ((row & 7) << 4)));
        }
#pragma unroll
        for (int n = 0; n < 2; n++) {
          int nr = ng * 32 + n * 16 + l15;
          bb[n] = *(short8*)(lds + WOF + half * 32768 + nr * 256 + ((kk * 64 + 16 * l4) ^ ((nr & 7) << 4)));
        }
#pragma unroll
        for (int m = 0; m < 2; m++)
#pragma unroll
          for (int n = 0; n < 2; n++)
            acc[m][n] = __builtin_amdgcn_mfma_f32_16x16x32_bf16(a[m], bb[n], acc[m][n], 0, 0, 0);
      }
#pragma unroll
      for (int n = 0; n < 2; n++) {
        int col = ng * 32 + n * 16 + l15;
        float addv = half ? 0.0f : add1g[col];
#pragma unroll
        for (int m = 0; m < 2; m++)
#pragma unroll
          for (int rr = 0; rr < 4; rr++) {
            int row = mg * 32 + m * 16 + l4 * 4 + rr;
            objSO[(size_t)(row0 + row) * 256 + half * 128 + col] =
                (unsigned short)f2bf(acc[m][n][rr] + addv);
          }
      }
    }
  }
}

// ---- edge MLP v11: barrier-free + 16 waves/CU + register-direct GEMM1->GEMM2.
// 1024 thr (16 waves), grid 256, LDS 97.25KB (w1p 32K + w2 64K + add2 1K).
// GEMM2 uses K=16 mfma so GEMM1's output quads feed it directly from registers
// (no h1 LDS round-trip). Each wave owns 8 tiles of 16 rows.
__global__ __launch_bounds__(1024, 1) void edge_mlp(
    const float* __restrict__ pred, const int* __restrict__ edges,
    const unsigned short* __restrict__ objSO,
    const short* __restrict__ w1t, const short* __restrict__ w2t,
    const float* __restrict__ add2g,
    float* __restrict__ out_p, unsigned short* __restrict__ o_scr)
{
  __shared__ __align__(16) char lds[99328];
  const int W1P = 0;        // 32K: w1p rows(h-col) 0..127 x 256B swz
  const int W2O = 32768;    // 64K: w2 rows(out-col) 0..255 x 256B swz
  const int ADD2 = 98304;   // 1K: add2 f32[256]

  int tid = threadIdx.x;
  // ---- init staging (only barrier in the kernel); 1024 threads
  {
    int n = tid >> 3, q = tid & 7;                 // 128 rows x 8 thr: 4B? -> use 2 rows/8thr
    // stage w1p: 128 rows x 256B; thread handles 32B
    int swz = (n & 7) << 4;
    const short* src = w1t + n * 384 + 128 + q * 16;
    short8 v0 = *(const short8*)(src);
    short8 v1 = *(const short8*)(src + 8);
    *(short8*)(lds + W1P + n * 256 + ((q * 32) ^ swz)) = v0;
    *(short8*)(lds + W1P + n * 256 + ((q * 32 + 16) ^ swz)) = v1;
  }
  {
    int n = tid >> 2, q = tid & 3;                 // 256 rows x 4 thr: 64B each
    int swz = (n & 7) << 4;
    const short* src = w2t + n * 128 + q * 32;
#pragma unroll
    for (int i = 0; i < 4; i++)
      *(short8*)(lds + W2O + n * 256 + ((q * 64 + i * 16) ^ swz)) = *(const short8*)(src + i * 8);
  }
  if (tid < 256) *(float*)(lds + ADD2 + tid * 4) = add2g[tid];
  __syncthreads();

  int wave = tid >> 6, lane = tid & 63;
  int l15 = lane & 15, l4 = lane >> 4;
  int hswz = (l15 & 7) << 4;

  size_t wrow0 = ((size_t)blockIdx.x * 16 + wave) * 128;   // 128 rows per wave
  int b_ = (int)(wrow0 >> 14);
  const char* soBase = (const char*)objSO + (size_t)b_ * On * 512;

  float4 pp[8];
  uint2 gsv[8], gov[8];
  int2 e;

  auto load_ep = [&](int j) {
    size_t gr = wrow0 + (size_t)j * 16 + l15;
    e = *(const int2*)&edges[gr * 2];
    const float* pr = pred + gr * 128 + l4 * 8;
#pragma unroll
    for (int kk = 0; kk < 4; kk++) {
      pp[2 * kk]     = *(const float4*)(pr + kk * 32);
      pp[2 * kk + 1] = *(const float4*)(pr + kk * 32 + 4);
    }
  };
  auto load_g = [&]() {
    const char* bs = soBase + (size_t)e.x * 512 + l4 * 8;
    const char* bo = soBase + (size_t)e.y * 512 + 256 + l4 * 8;
#pragma unroll
    for (int n = 0; n < 8; n++) {
      gsv[n] = *(const uint2*)(bs + n * 32);
      gov[n] = *(const uint2*)(bo + n * 32);
    }
  };

  load_ep(0);
  load_g();

  for (int j = 0; j < 8; ++j) {
    size_t gr = wrow0 + (size_t)j * 16 + l15;

    // ---- A-frags from pred regs (bf16 pack)
    short8 af[4];
#pragma unroll
    for (int kk = 0; kk < 4; kk++) {
      float4 a0 = pp[2 * kk], a1 = pp[2 * kk + 1];
      short8 a;
      a[0]=f2bf(a0.x); a[1]=f2bf(a0.y); a[2]=f2bf(a0.z); a[3]=f2bf(a0.w);
      a[4]=f2bf(a1.x); a[5]=f2bf(a1.y); a[6]=f2bf(a1.z); a[7]=f2bf(a1.w);
      af[kk] = a;
    }
    if (j + 1 < 8) load_ep(j + 1);    // pp free; e overwritten (j's g already in regs)

    // ---- GEMM1 (K=32, transposed): acc1[n][rr] = h[t=l15][col=n*16+l4*4+rr]
    f32x4 acc1[8] = {};
    __builtin_amdgcn_s_setprio(1);
#pragma unroll
    for (int kk = 0; kk < 4; kk++) {
#pragma unroll
      for (int n = 0; n < 8; n++) {
        short8 wf = *(short8*)(lds + W1P + (n * 16 + l15) * 256 + ((kk * 64 + 16 * l4) ^ hswz));
        acc1[n] = __builtin_amdgcn_mfma_f32_16x16x32_bf16(wf, af[kk], acc1[n], 0, 0, 0);
      }
    }
    __builtin_amdgcn_s_setprio(0);

    // ---- epi1: h = relu(acc1 + gS + gO) -> packed bf16 K16 B-frags (REGISTERS)
    short4v hb[8];
#pragma unroll
    for (int n = 0; n < 8; n++) {
      float v0 = fmaxf(acc1[n][0] + bflo(gsv[n].x) + bflo(gov[n].x), 0.0f);
      float v1 = fmaxf(acc1[n][1] + bfhi(gsv[n].x) + bfhi(gov[n].x), 0.0f);
      float v2 = fmaxf(acc1[n][2] + bflo(gsv[n].y) + bflo(gov[n].y), 0.0f);
      float v3 = fmaxf(acc1[n][3] + bfhi(gsv[n].y) + bfhi(gov[n].y), 0.0f);
      union { uint32_t u[2]; short4v v; } cv;
      cv.u[0] = pack2bf(v0, v1);
      cv.u[1] = pack2bf(v2, v3);
      hb[n] = cv.v;
    }
    if (j + 1 < 8) load_g();          // g for j+1 (uses the new e)

    // ---- GEMM2: 16 col-groups x 8 K16-mfma, A=w2 frag (8B LDS), B=hb (regs)
#pragma unroll
    for (int cg = 0; cg < 16; cg++) {
      f32x4 acc2 = {};
      const char* wbase = lds + W2O + (size_t)(cg * 16 + l15) * 256;
      __builtin_amdgcn_s_setprio(1);
#pragma unroll
      for (int n = 0; n < 8; n++) {
        short4v wf = *(const short4v*)(wbase + ((n * 32 + l4 * 8) ^ hswz));
        acc2 = __builtin_amdgcn_mfma_f32_16x16x16bf16_1k(wf, hb[n], acc2, 0, 0, 0);
      }
      __builtin_amdgcn_s_setprio(0);
      int colp = cg * 16 + l4 * 4;     // 0..255
      float4 ad = *(float4*)(lds + ADD2 + colp * 4);
      float v0 = fmaxf(acc2[0] + ad.x, 0.0f);
      float v1 = fmaxf(acc2[1] + ad.y, 0.0f);
      float v2 = fmaxf(acc2[2] + ad.z, 0.0f);
      float v3 = fmaxf(acc2[3] + ad.w, 0.0f);
      if (cg < 8) {
        float4 ov; ov.x = v0; ov.y = v1; ov.z = v2; ov.w = v3;
        *(float4*)(out_p + gr * 128 + colp) = ov;
      } else {
        uint2 od; od.x = pack2bf(v0, v1); od.y = pack2bf(v2, v3);
        *(uint2*)((char*)o_scr + gr * 256 + (colp - 128) * 2) = od;
      }
    }
  }
}

// ---- object MLP (pooling fused): gather-mean from o_scr, GEMM3 -> GEMM4 (prescaled w)
__global__ __launch_bounds__(256) void obj_mlp(
    const unsigned short* __restrict__ o_scr, const int* __restrict__ hist,
    const int* __restrict__ offs, const unsigned short* __restrict__ eidx,
    float* __restrict__ out_obj,
    const short* __restrict__ w3t, const short* __restrict__ w4t,
    const float* __restrict__ add3g, const float* __restrict__ add4g)
{
  __shared__ short xs[64][136];
  __shared__ short hs[64][136];
  int row0 = blockIdx.x * 64;
  int tid = threadIdx.x;

  {
    int r = tid >> 2, seg = tid & 3;
    int rg = row0 + r;
    int bb_ = rg >> 12;
    int cnt = hist[rg], start = offs[rg];
    float sum[32];
#pragma unroll
    for (int j = 0; j < 32; j++) sum[j] = 0.f;
    for (int k = 0; k < cnt; k++) {
      int t = eidx[start + k];
      const unsigned short* src = o_scr + ((size_t)(bb_ * Tn + t)) * 128 + seg * 32;
#pragma unroll
      for (int i = 0; i < 4; i++) {
        short8 v = *(const short8*)(src + i * 8);
#pragma unroll
        for (int j = 0; j < 8; j++) sum[i * 8 + j] += bf2f((unsigned short)v[j]);
      }
    }
    float ic = 1.0f / fmaxf((float)cnt, 1.0f);
#pragma unroll
    for (int i = 0; i < 4; i++) {
      short8 pk;
#pragma unroll
      for (int j = 0; j < 8; j++) pk[j] = f2bf(sum[i * 8 + j] * ic);
      *(short8*)&xs[r][seg * 32 + i * 8] = pk;
    }
  }
  __syncthreads();

  int wave = tid >> 6, lane = tid & 63;
  int l15 = lane & 15, l4 = lane >> 4;
  int n0 = wave * 32;

  short8 w3r[2][4], w4r[2][4];
#pragma unroll
  for (int n = 0; n < 2; n++)
#pragma unroll
    for (int kk = 0; kk < 4; kk++) {
      w3r[n][kk] = *(const short8*)&w3t[(n0 + n * 16 + l15) * 128 + kk * 32 + 8 * l4];
      w4r[n][kk] = *(const short8*)&w4t[(n0 + n * 16 + l15) * 128 + kk * 32 + 8 * l4];
    }

  f32x4 acc[4][2] = {};
#pragma unroll
  for (int kk = 0; kk < 4; kk++) {
    int k0 = kk * 32;
    short8 a[4];
#pragma unroll
    for (int m = 0; m < 4; m++) a[m] = *(short8*)&xs[m * 16 + l15][k0 + 8 * l4];
#pragma unroll
    for (int m = 0; m < 4; m++)
#pragma unroll
      for (int n = 0; n < 2; n++)
        acc[m][n] = __builtin_amdgcn_mfma_f32_16x16x32_bf16(a[m], w3r[n][kk], acc[m][n], 0, 0, 0);
  }
#pragma unroll
  for (int n = 0; n < 2; n++) {
    int col = n0 + n * 16 + l15;
    float ad = add3g[col];
#pragma unroll
    for (int m = 0; m < 4; m++)
#pragma unroll
      for (int rr = 0; rr < 4; rr++) {
        float v = fmaxf(acc[m][n][rr] + ad, 0.0f);
        hs[m * 16 + l4 * 4 + rr][col] = f2bf(v);
      }
  }
  __syncthreads();

  f32x4 acc2[4][2] = {};
#pragma unroll
  for (int kk = 0; kk < 4; kk++) {
    int k0 = kk * 32;
    short8 a[4];
#pragma unroll
    for (int m = 0; m < 4; m++) a[m] = *(short8*)&hs[m * 16 + l15][k0 + 8 * l4];
#pragma unroll
    for (int m = 0; m < 4; m++)
#pragma unroll
      for (int n = 0; n < 2; n++)
        acc2[m][n] = __builtin_amdgcn_mfma_f32_16x16x32_bf16(a[m], w4r[n][kk], acc2[m][n], 0, 0, 0);
  }
#pragma unroll
  for (int n = 0; n < 2; n++) {
    int col = n0 + n * 16 + l15;
    float ad = add4g[col];
#pragma unroll
    for (int m = 0; m < 4; m++)
#pragma unroll
      for (int rr = 0; rr < 4; rr++) {
        int row = m * 16 + l4 * 4 + rr;
        float v = fmaxf(acc2[m][n][rr] + ad, 0.0f);
        out_obj[(size_t)(row0 + row) * 128 + col] = v;
      }
  }
}

extern "C" void kernel_launch(void* const* d_in, const int* in_sizes, int n_in,
                              void* d_out, int out_size, void* d_ws, size_t ws_size,
                              hipStream_t stream) {
  const float* obj  = (const float*)d_in[0];
  const float* pred = (const float*)d_in[1];
  const int*   edges= (const int*)d_in[2];
  const float* W1 = (const float*)d_in[3];
  const float* b1 = (const float*)d_in[4];
  const float* g1 = (const float*)d_in[5];
  const float* be1= (const float*)d_in[6];
  const float* W2 = (const float*)d_in[7];
  const float* b2 = (const float*)d_in[8];
  const float* g2 = (const float*)d_in[9];
  const float* be2= (const float*)d_in[10];
  const float* W3 = (const float*)d_in[11];
  const float* b3 = (const float*)d_in[12];
  const float* g3 = (const float*)d_in[13];
  const float* be3= (const float*)d_in[14];
  const float* W4 = (const float*)d_in[15];
  const float* b4 = (const float*)d_in[16];
  const float* g4 = (const float*)d_in[17];
  const float* be4= (const float*)d_in[18];

  float* out_obj = (float*)d_out;                           // B*O*128
  float* out_p   = (float*)d_out + (size_t)Bn * On * 128;   // B*T*128
  // objSO (bf16 B*O*256 = 67 MB) lives in the out_obj region (dead until obj_mlp)
  unsigned short* objSO = (unsigned short*)d_out;

  char* ws = (char*)d_ws;
  short* w1t = (short*)(ws);
  short* w2t = (short*)(ws + 49152 * 2);
  short* w3t = (short*)(ws + (49152 + 32768) * 2);
  short* w4t = (short*)(ws + (49152 + 32768 + 16384) * 2);
  float* add1g = (float*)(ws + 229376);
  float* add2g = (float*)(ws + 229888);
  float* add3g = (float*)(ws + 230912);
  float* add4g = (float*)(ws + 231424);

  const size_t OFF_HIST = 262144;
  const size_t OFF_OFFS = OFF_HIST + 524288;
  const size_t OFF_EIDX = OFF_OFFS + 1048576;     // u16 B*T = 1 MB
  const size_t OFF_OSCR = 4194304;                // bf16 B*T*128 = 128 MiB

  int* hist = (int*)(ws + OFF_HIST);
  int* offs = (int*)(ws + OFF_OFFS);
  unsigned short* eidx = (unsigned short*)(ws + OFF_EIDX);
  unsigned short* o_scr = (unsigned short*)(ws + OFF_OSCR);

  prep_sort<<<145, 1024, 0, stream>>>(edges, hist, offs, eidx,
      W1, W2, W3, W4, b1, g1, be1, b2, g2, be2, b3, g3, be3, b4, g4, be4,
      w1t, w2t, w3t, w4t, add1g, add2g, add3g, add4g);
  objproj<<<512, 512, 0, stream>>>(obj, w1t, add1g, objSO);
  edge_mlp<<<256, 1024, 0, stream>>>(pred, edges, objSO, w1t, w2t, add2g,
      out_p, o_scr);
  obj_mlp<<<(Bn * On) / 64, 256, 0, stream>>>(o_scr, hist, offs, eidx, out_obj,
      w3t, w4t, add3g, add4g);
}

// Round 14
// 320.936 us; speedup vs baseline: 2.7393x; 2.7393x over previous
//
#include <hip/hip_runtime.h>
#include <hip/hip_bf16.h>
#include <stdint.h>

// GraphTripleConv: B=32, O=4096, T=16384, D=H=DOUT=128
// out = [new_obj (B*O*128) | new_p (B*T*128)], f32
#define Bn 32
#define On 4096
#define Tn 16384
#define Dn 128

typedef short short8 __attribute__((ext_vector_type(8)));
typedef float f32x4 __attribute__((ext_vector_type(4)));

__device__ inline short f2bf(float f) {
  union { float f; uint32_t u; } v; v.f = f;
  uint32_t u = v.u;
  uint32_t r = u + 0x7fffu + ((u >> 16) & 1u);  // RNE
  return (short)(r >> 16);
}
__device__ inline float bf2f(unsigned short u) {
  union { uint32_t ui; float f; } cv; cv.ui = ((uint32_t)u) << 16; return cv.f;
}
__device__ inline uint32_t pack2bf(float a, float b) {
  return ((uint32_t)(uint16_t)f2bf(a)) | (((uint32_t)(uint16_t)f2bf(b)) << 16);
}
__device__ inline float bflo(uint32_t u) { union { uint32_t i; float f; } c; c.i = u << 16; return c.f; }
__device__ inline float bfhi(uint32_t u) { union { uint32_t i; float f; } c; c.i = u & 0xffff0000u; return c.f; }

// ---- fused prep+sort (one launch): blocks 0..31 = per-batch counting sort;
// blocks 32..144 = weight prep (f32 [K][N] -> bf16 [N][K], prescaled by g*invs).
__global__ __launch_bounds__(1024) void prep_sort(
    const int* __restrict__ edges, int* __restrict__ hist_g,
    int* __restrict__ offs_g, unsigned short* __restrict__ eidx,
    const float* __restrict__ W1, const float* __restrict__ W2,
    const float* __restrict__ W3, const float* __restrict__ W4,
    const float* __restrict__ b1, const float* __restrict__ g1, const float* __restrict__ be1,
    const float* __restrict__ b2, const float* __restrict__ g2, const float* __restrict__ be2,
    const float* __restrict__ b3, const float* __restrict__ g3, const float* __restrict__ be3,
    const float* __restrict__ b4, const float* __restrict__ g4, const float* __restrict__ be4,
    short* __restrict__ w1t, short* __restrict__ w2t,
    short* __restrict__ w3t, short* __restrict__ w4t,
    float* __restrict__ add1g, float* __restrict__ add2g,
    float* __restrict__ add3g, float* __restrict__ add4g)
{
  if (blockIdx.x >= 32) {
    const float invs = 1.0f / sqrtf(1.001f);
    int i = (blockIdx.x - 32) * 1024 + threadIdx.x;
    if (i < 49152) {
      int n = i / 384, k = i % 384;
      w1t[i] = f2bf(W1[k * 128 + n] * g1[n] * invs);
    } else if (i < 81920) {
      int j = i - 49152;
      int n = j / 128, k = j % 128;
      int c2 = 128 + n;                       // only cols 128..383 live (new_s dead)
      w2t[j] = f2bf(W2[k * 384 + c2] * g2[c2] * invs);
    } else if (i < 98304) {
      int j = i - 81920;
      int n = j / 128, k = j % 128;
      w3t[j] = f2bf(W3[k * 128 + n] * g3[n] * invs);
    } else if (i < 114688) {
      int j = i - 98304;
      int n = j / 128, k = j % 128;
      w4t[j] = f2bf(W4[k * 128 + n] * g4[n] * invs);
    } else if (i < 114816) {
      int n = i - 114688;
      add1g[n] = b1[n] * g1[n] * invs + be1[n];
    } else if (i < 115072) {
      int n = i - 114816;
      int c2 = 128 + n;
      add2g[n] = b2[c2] * g2[c2] * invs + be2[c2];
    } else if (i < 115200) {
      int n = i - 115072;
      add3g[n] = b3[n] * g3[n] * invs + be3[n];
    } else if (i < 115328) {
      int n = i - 115200;
      add4g[n] = b4[n] * g4[n] * invs + be4[n];
    }
    return;
  }
  // ---- sort path
  __shared__ int h[4096];
  __shared__ int of[4096];
  __shared__ int sd[1024];
  int b = blockIdx.x, tid = threadIdx.x;
#pragma unroll
  for (int i = 0; i < 4; i++) h[tid + i * 1024] = 0;
  __syncthreads();
  int ov[16];
#pragma unroll
  for (int j = 0; j < 16; j++) {
    int t = j * 1024 + tid;
    ov[j] = edges[((size_t)(b * Tn + t)) * 2 + 1];
    atomicAdd(&h[ov[j]], 1);
  }
  __syncthreads();
  int base = tid * 4;
  int hh[4]; int s = 0;
#pragma unroll
  for (int j = 0; j < 4; j++) { hh[j] = h[base + j]; s += hh[j]; }
  sd[tid] = s;
  int tsum = s;
  for (int off = 1; off < 1024; off <<= 1) {
    __syncthreads();
    int t = (tid >= off) ? sd[tid - off] : 0;
    __syncthreads();
    sd[tid] += t;
  }
  __syncthreads();
  int excl = sd[tid] - tsum + b * Tn;
#pragma unroll
  for (int j = 0; j < 4; j++) {
    of[base + j] = excl;
    offs_g[b * On + base + j] = excl;
    hist_g[b * On + base + j] = hh[j];
    excl += hh[j];
  }
  __syncthreads();
#pragma unroll
  for (int i = 0; i < 4; i++) h[tid + i * 1024] = 0;   // reuse as fill
  __syncthreads();
#pragma unroll
  for (int j = 0; j < 16; j++) {
    int t = j * 1024 + tid;
    int pos = of[ov[j]] + atomicAdd(&h[ov[j]], 1);
    eidx[pos] = (unsigned short)t;
  }
}

// ---- object projection: objSO[r] = [ objS*gs1+add1 | objO*gs1 ], bf16 (prescaled w1t)
__global__ __launch_bounds__(512, 2) void objproj(
    const float* __restrict__ obj, const short* __restrict__ w1t,
    const float* __restrict__ add1g, unsigned short* __restrict__ objSO)
{
  __shared__ __align__(16) char lds[81920];
  const int WOF = 0, AOF = 65536;
  int tid = threadIdx.x;
  {
    int n = tid >> 2, q = tid & 3;
    int swz = (n & 7) << 4;
    const short* s1 = w1t + n * 384 + q * 32;          // W1s: k 0..127
    const short* s2 = w1t + n * 384 + 256 + q * 32;    // W1o: k 256..383
#pragma unroll
    for (int i = 0; i < 4; i++) {
      *(short8*)(lds + WOF + n * 256 + ((q * 64 + i * 16) ^ swz)) = *(const short8*)(s1 + i * 8);
      *(short8*)(lds + WOF + 32768 + n * 256 + ((q * 64 + i * 16) ^ swz)) = *(const short8*)(s2 + i * 8);
    }
  }
  int wave = tid >> 6, lane = tid & 63;
  int l15 = lane & 15, l4 = lane >> 4;
  int mg = wave >> 2, ng = wave & 3;
  int r = tid >> 3, seg = tid & 7;
  int rswz = (r & 7) << 4;

  for (int it = 0; it < 4; it++) {
    int row0 = (blockIdx.x * 4 + it) * 64;
    if (it) __syncthreads();
    {
      const float* src = obj + (size_t)(row0 + r) * Dn + seg * 16;
      float4 v0 = *(const float4*)(src);
      float4 v1 = *(const float4*)(src + 4);
      float4 v2 = *(const float4*)(src + 8);
      float4 v3 = *(const float4*)(src + 12);
      short8 p0, p1;
      p0[0]=f2bf(v0.x); p0[1]=f2bf(v0.y); p0[2]=f2bf(v0.z); p0[3]=f2bf(v0.w);
      p0[4]=f2bf(v1.x); p0[5]=f2bf(v1.y); p0[6]=f2bf(v1.z); p0[7]=f2bf(v1.w);
      p1[0]=f2bf(v2.x); p1[1]=f2bf(v2.y); p1[2]=f2bf(v2.z); p1[3]=f2bf(v2.w);
      p1[4]=f2bf(v3.x); p1[5]=f2bf(v3.y); p1[6]=f2bf(v3.z); p1[7]=f2bf(v3.w);
      *(short8*)(lds + AOF + r * 256 + ((seg * 32) ^ rswz)) = p0;
      *(short8*)(lds + AOF + r * 256 + ((seg * 32 + 16) ^ rswz)) = p1;
    }
    __syncthreads();
#pragma unroll
    for (int half = 0; half < 2; half++) {
      f32x4 acc[2][2] = {};
#pragma unroll
      for (int kk = 0; kk < 4; kk++) {
        short8 a[2], bb[2];
#pragma unroll
        for (int m = 0; m < 2; m++) {
          int row = mg * 32 + m * 16 + l15;
          a[m] = *(short8*)(lds + AOF + row * 256 + ((kk * 64 + 16 * l4) ^ ((row & 7) << 4)));
        }
#pragma unroll
        for (int n = 0; n < 2; n++) {
          int nr = ng * 32 + n * 16 + l15;
          bb[n] = *(short8*)(lds + WOF + half * 32768 + nr * 256 + ((kk * 64 + 16 * l4) ^ ((nr & 7) << 4)));
        }
#pragma unroll
        for (int m = 0; m < 2; m++)
#pragma unroll
          for (int n = 0; n < 2; n++)
            acc[m][n] = __builtin_amdgcn_mfma_f32_16x16x32_bf16(a[m], bb[n], acc[m][n], 0, 0, 0);
      }
#pragma unroll
      for (int n = 0; n < 2; n++) {
        int col = ng * 32 + n * 16 + l15;
        float addv = half ? 0.0f : add1g[col];
#pragma unroll
        for (int m = 0; m < 2; m++)
#pragma unroll
          for (int rr = 0; rr < 4; rr++) {
            int row = mg * 32 + m * 16 + l4 * 4 + rr;
            objSO[(size_t)(row0 + row) * 256 + half * 128 + col] =
                (unsigned short)f2bf(acc[m][n][rr] + addv);
          }
      }
    }
  }
}

// ---- edge MLP v12: v10 barrier-free pipeline + batch-affine XCD swizzle.
// grid 1024 x 512thr; block = 512 rows; all ~32 resident blocks of an XCD work
// the SAME batch so the batch's objSO slice (2.1MB) lives in that XCD's L2.
__global__ __launch_bounds__(512, 2) void edge_mlp(
    const float* __restrict__ pred, const int* __restrict__ edges,
    const unsigned short* __restrict__ objSO,
    const short* __restrict__ w1t, const short* __restrict__ w2t,
    const float* __restrict__ add2g,
    float* __restrict__ out_p, unsigned short* __restrict__ o_scr)
{
  __shared__ __align__(16) char lds[132096];
  const int W1P = 0;        // 32K: w1p rows(h-col) 0..127 x 256B swz
  const int W2O = 32768;    // 64K: w2 rows(out-col) 0..255 x 256B swz
  const int ADD2 = 98304;   // 1K: add2 f32[256]
  const int H1B = 99328;    // 8 x 4K wave-private h1

  int tid = threadIdx.x;
  // ---- init staging (only block-wide barrier in the kernel)
  {
    int n = tid >> 2, q = tid & 3;
    int swz = (n & 7) << 4;
    const short* src = w1t + n * 384 + 128 + q * 32;
#pragma unroll
    for (int i = 0; i < 4; i++)
      *(short8*)(lds + W1P + n * 256 + ((q * 64 + i * 16) ^ swz)) = *(const short8*)(src + i * 8);
  }
  {
    int n = tid >> 1, q = tid & 1;
    int swz = (n & 7) << 4;
    const short* src = w2t + n * 128 + q * 64;
#pragma unroll
    for (int i = 0; i < 8; i++)
      *(short8*)(lds + W2O + n * 256 + ((q * 128 + i * 16) ^ swz)) = *(const short8*)(src + i * 8);
  }
  if (tid < 256) *(float*)(lds + ADD2 + tid * 4) = add2g[tid];
  __syncthreads();

  int wave = tid >> 6, lane = tid & 63;
  int l15 = lane & 15, l4 = lane >> 4;
  char* h1w = lds + H1B + wave * 4096;
  int hswz = (l15 & 7) << 4;

  // batch-affine mapping: xcd = p&7 gets batches xcd, xcd+8, xcd+16, xcd+24
  int p = blockIdx.x;
  int xcd = p & 7, slot = p >> 3;
  int b_ = xcd + 8 * (slot >> 5);
  int blkin = slot & 31;
  size_t wrow0 = (size_t)b_ * Tn + (size_t)blkin * 512 + (size_t)wave * 64;
  const char* soBase = (const char*)objSO + (size_t)b_ * On * 512;

  float4 pp[8];
  uint2 gsv[8], gov[8];
  int2 e;

  auto load_ep = [&](int j) {
    size_t gr = wrow0 + (size_t)j * 16 + l15;
    e = *(const int2*)&edges[gr * 2];
    const float* pr = pred + gr * 128 + l4 * 8;
#pragma unroll
    for (int kk = 0; kk < 4; kk++) {
      pp[2 * kk]     = *(const float4*)(pr + kk * 32);
      pp[2 * kk + 1] = *(const float4*)(pr + kk * 32 + 4);
    }
  };
  auto load_g = [&]() {
    const char* bs = soBase + (size_t)e.x * 512 + l4 * 8;
    const char* bo = soBase + (size_t)e.y * 512 + 256 + l4 * 8;
#pragma unroll
    for (int n = 0; n < 8; n++) {
      gsv[n] = *(const uint2*)(bs + n * 32);
      gov[n] = *(const uint2*)(bo + n * 32);
    }
  };

  load_ep(0);
  load_g();

  for (int j = 0; j < 4; ++j) {
    size_t gr = wrow0 + (size_t)j * 16 + l15;

    // ---- A-frags from pred regs (bf16 pack)
    short8 af[4];
#pragma unroll
    for (int kk = 0; kk < 4; kk++) {
      float4 a0 = pp[2 * kk], a1 = pp[2 * kk + 1];
      short8 a;
      a[0]=f2bf(a0.x); a[1]=f2bf(a0.y); a[2]=f2bf(a0.z); a[3]=f2bf(a0.w);
      a[4]=f2bf(a1.x); a[5]=f2bf(a1.y); a[6]=f2bf(a1.z); a[7]=f2bf(a1.w);
      af[kk] = a;
    }
    if (j + 1 < 4) load_ep(j + 1);    // pp free; e overwritten (j's g already in regs)

    // ---- GEMM1 (transposed): acc1[n][rr] = h[row=l15][col=n*16+l4*4+rr]
    f32x4 acc1[8] = {};
    __builtin_amdgcn_s_setprio(1);
#pragma unroll
    for (int kk = 0; kk < 4; kk++) {
#pragma unroll
      for (int n = 0; n < 8; n++) {
        short8 wf = *(short8*)(lds + W1P + (n * 16 + l15) * 256 + ((kk * 64 + 16 * l4) ^ hswz));
        acc1[n] = __builtin_amdgcn_mfma_f32_16x16x32_bf16(wf, af[kk], acc1[n], 0, 0, 0);
      }
    }
    __builtin_amdgcn_s_setprio(0);

    // ---- epi1: h = relu(acc1 + gS + gO) -> bf16 -> wave-private LDS
#pragma unroll
    for (int n = 0; n < 8; n++) {
      float v0 = fmaxf(acc1[n][0] + bflo(gsv[n].x) + bflo(gov[n].x), 0.0f);
      float v1 = fmaxf(acc1[n][1] + bfhi(gsv[n].x) + bfhi(gov[n].x), 0.0f);
      float v2 = fmaxf(acc1[n][2] + bflo(gsv[n].y) + bflo(gov[n].y), 0.0f);
      float v3 = fmaxf(acc1[n][3] + bfhi(gsv[n].y) + bfhi(gov[n].y), 0.0f);
      uint2 hd; hd.x = pack2bf(v0, v1); hd.y = pack2bf(v2, v3);
      *(uint2*)(h1w + l15 * 256 + ((n * 32 + l4 * 8) ^ hswz)) = hd;
    }
    if (j + 1 < 4) load_g();          // g for j+1 (uses the new e)

    // ---- h1 frags back (wave-private: lgkm-only dependency, no barrier)
    short8 af2[4];
#pragma unroll
    for (int kk = 0; kk < 4; kk++)
      af2[kk] = *(short8*)(h1w + l15 * 256 + ((kk * 64 + 16 * l4) ^ hswz));

    // ---- GEMM2 in two col-halves (reuse acc regs)
#pragma unroll
    for (int half = 0; half < 2; half++) {
      f32x4 acc2[8] = {};
      __builtin_amdgcn_s_setprio(1);
#pragma unroll
      for (int kk = 0; kk < 4; kk++) {
#pragma unroll
        for (int n = 0; n < 8; n++) {
          short8 wf = *(short8*)(lds + W2O + (half * 128 + n * 16 + l15) * 256 + ((kk * 64 + 16 * l4) ^ hswz));
          acc2[n] = __builtin_amdgcn_mfma_f32_16x16x32_bf16(wf, af2[kk], acc2[n], 0, 0, 0);
        }
      }
      __builtin_amdgcn_s_setprio(0);
      if (half == 0) {
#pragma unroll
        for (int n = 0; n < 8; n++) {
          float4 ad = *(float4*)(lds + ADD2 + (n * 16 + l4 * 4) * 4);
          float4 ov;
          ov.x = fmaxf(acc2[n][0] + ad.x, 0.0f);
          ov.y = fmaxf(acc2[n][1] + ad.y, 0.0f);
          ov.z = fmaxf(acc2[n][2] + ad.z, 0.0f);
          ov.w = fmaxf(acc2[n][3] + ad.w, 0.0f);
          *(float4*)(out_p + gr * 128 + n * 16 + l4 * 4) = ov;
        }
      } else {
#pragma unroll
        for (int n = 0; n < 8; n++) {
          float4 ad = *(float4*)(lds + ADD2 + 512 + (n * 16 + l4 * 4) * 4);
          float v0 = fmaxf(acc2[n][0] + ad.x, 0.0f);
          float v1 = fmaxf(acc2[n][1] + ad.y, 0.0f);
          float v2 = fmaxf(acc2[n][2] + ad.z, 0.0f);
          float v3 = fmaxf(acc2[n][3] + ad.w, 0.0f);
          uint2 od; od.x = pack2bf(v0, v1); od.y = pack2bf(v2, v3);
          *(uint2*)((char*)o_scr + gr * 256 + (n * 16 + l4 * 4) * 2) = od;
        }
      }
    }
  }
}

// ---- object MLP (pooling fused): gather-mean from o_scr, GEMM3 -> GEMM4 (prescaled w)
__global__ __launch_bounds__(256) void obj_mlp(
    const unsigned short* __restrict__ o_scr, const int* __restrict__ hist,
    const int* __restrict__ offs, const unsigned short* __restrict__ eidx,
    float* __restrict__ out_obj,
    const short* __restrict__ w3t, const short* __restrict__ w4t,
    const float* __restrict__ add3g, const float* __restrict__ add4g)
{
  __shared__ short xs[64][136];
  __shared__ short hs[64][136];
  int row0 = blockIdx.x * 64;
  int tid = threadIdx.x;

  {
    int r = tid >> 2, seg = tid & 3;
    int rg = row0 + r;
    int bb_ = rg >> 12;
    int cnt = hist[rg], start = offs[rg];
    float sum[32];
#pragma unroll
    for (int j = 0; j < 32; j++) sum[j] = 0.f;
    for (int k = 0; k < cnt; k++) {
      int t = eidx[start + k];
      const unsigned short* src = o_scr + ((size_t)(bb_ * Tn + t)) * 128 + seg * 32;
#pragma unroll
      for (int i = 0; i < 4; i++) {
        short8 v = *(const short8*)(src + i * 8);
#pragma unroll
        for (int j = 0; j < 8; j++) sum[i * 8 + j] += bf2f((unsigned short)v[j]);
      }
    }
    float ic = 1.0f / fmaxf((float)cnt, 1.0f);
#pragma unroll
    for (int i = 0; i < 4; i++) {
      short8 pk;
#pragma unroll
      for (int j = 0; j < 8; j++) pk[j] = f2bf(sum[i * 8 + j] * ic);
      *(short8*)&xs[r][seg * 32 + i * 8] = pk;
    }
  }
  __syncthreads();

  int wave = tid >> 6, lane = tid & 63;
  int l15 = lane & 15, l4 = lane >> 4;
  int n0 = wave * 32;

  short8 w3r[2][4], w4r[2][4];
#pragma unroll
  for (int n = 0; n < 2; n++)
#pragma unroll
    for (int kk = 0; kk < 4; kk++) {
      w3r[n][kk] = *(const short8*)&w3t[(n0 + n * 16 + l15) * 128 + kk * 32 + 8 * l4];
      w4r[n][kk] = *(const short8*)&w4t[(n0 + n * 16 + l15) * 128 + kk * 32 + 8 * l4];
    }

  f32x4 acc[4][2] = {};
#pragma unroll
  for (int kk = 0; kk < 4; kk++) {
    int k0 = kk * 32;
    short8 a[4];
#pragma unroll
    for (int m = 0; m < 4; m++) a[m] = *(short8*)&xs[m * 16 + l15][k0 + 8 * l4];
#pragma unroll
    for (int m = 0; m < 4; m++)
#pragma unroll
      for (int n = 0; n < 2; n++)
        acc[m][n] = __builtin_amdgcn_mfma_f32_16x16x32_bf16(a[m], w3r[n][kk], acc[m][n], 0, 0, 0);
  }
#pragma unroll
  for (int n = 0; n < 2; n++) {
    int col = n0 + n * 16 + l15;
    float ad = add3g[col];
#pragma unroll
    for (int m = 0; m < 4; m++)
#pragma unroll
      for (int rr = 0; rr < 4; rr++) {
        float v = fmaxf(acc[m][n][rr] + ad, 0.0f);
        hs[m * 16 + l4 * 4 + rr][col] = f2bf(v);
      }
  }
  __syncthreads();

  f32x4 acc2[4][2] = {};
#pragma unroll
  for (int kk = 0; kk < 4; kk++) {
    int k0 = kk * 32;
    short8 a[4];
#pragma unroll
    for (int m = 0; m < 4; m++) a[m] = *(short8*)&hs[m * 16 + l15][k0 + 8 * l4];
#pragma unroll
    for (int m = 0; m < 4; m++)
#pragma unroll
      for (int n = 0; n < 2; n++)
        acc2[m][n] = __builtin_amdgcn_mfma_f32_16x16x32_bf16(a[m], w4r[n][kk], acc2[m][n], 0, 0, 0);
  }
#pragma unroll
  for (int n = 0; n < 2; n++) {
    int col = n0 + n * 16 + l15;
    float ad = add4g[col];
#pragma unroll
    for (int m = 0; m < 4; m++)
#pragma unroll
      for (int rr = 0; rr < 4; rr++) {
        int row = m * 16 + l4 * 4 + rr;
        float v = fmaxf(acc2[m][n][rr] + ad, 0.0f);
        out_obj[(size_t)(row0 + row) * 128 + col] = v;
      }
  }
}

extern "C" void kernel_launch(void* const* d_in, const int* in_sizes, int n_in,
                              void* d_out, int out_size, void* d_ws, size_t ws_size,
                              hipStream_t stream) {
  const float* obj  = (const float*)d_in[0];
  const float* pred = (const float*)d_in[1];
  const int*   edges= (const int*)d_in[2];
  const float* W1 = (const float*)d_in[3];
  const float* b1 = (const float*)d_in[4];
  const float* g1 = (const float*)d_in[5];
  const float* be1= (const float*)d_in[6];
  const float* W2 = (const float*)d_in[7];
  const float* b2 = (const float*)d_in[8];
  const float* g2 = (const float*)d_in[9];
  const float* be2= (const float*)d_in[10];
  const float* W3 = (const float*)d_in[11];
  const float* b3 = (const float*)d_in[12];
  const float* g3 = (const float*)d_in[13];
  const float* be3= (const float*)d_in[14];
  const float* W4 = (const float*)d_in[15];
  const float* b4 = (const float*)d_in[16];
  const float* g4 = (const float*)d_in[17];
  const float* be4= (const float*)d_in[18];

  float* out_obj = (float*)d_out;                           // B*O*128
  float* out_p   = (float*)d_out + (size_t)Bn * On * 128;   // B*T*128
  // objSO (bf16 B*O*256 = 67 MB) lives in the out_obj region (dead until obj_mlp)
  unsigned short* objSO = (unsigned short*)d_out;

  char* ws = (char*)d_ws;
  short* w1t = (short*)(ws);
  short* w2t = (short*)(ws + 49152 * 2);
  short* w3t = (short*)(ws + (49152 + 32768) * 2);
  short* w4t = (short*)(ws + (49152 + 32768 + 16384) * 2);
  float* add1g = (float*)(ws + 229376);
  float* add2g = (float*)(ws + 229888);
  float* add3g = (float*)(ws + 230912);
  float* add4g = (float*)(ws + 231424);

  const size_t OFF_HIST = 262144;
  const size_t OFF_OFFS = OFF_HIST + 524288;
  const size_t OFF_EIDX = OFF_OFFS + 1048576;     // u16 B*T = 1 MB
  const size_t OFF_OSCR = 4194304;                // bf16 B*T*128 = 128 MiB

  int* hist = (int*)(ws + OFF_HIST);
  int* offs = (int*)(ws + OFF_OFFS);
  unsigned short* eidx = (unsigned short*)(ws + OFF_EIDX);
  unsigned short* o_scr = (unsigned short*)(ws + OFF_OSCR);

  prep_sort<<<145, 1024, 0, stream>>>(edges, hist, offs, eidx,
      W1, W2, W3, W4, b1, g1, be1, b2, g2, be2, b3, g3, be3, b4, g4, be4,
      w1t, w2t, w3t, w4t, add1g, add2g, add3g, add4g);
  objproj<<<512, 512, 0, stream>>>(obj, w1t, add1g, objSO);
  edge_mlp<<<1024, 512, 0, stream>>>(pred, edges, objSO, w1t, w2t, add2g,
      out_p, o_scr);
  obj_mlp<<<(Bn * On) / 64, 256, 0, stream>>>(o_scr, hist, offs, eidx, out_obj,
      w3t, w4t, add3g, add4g);
}